// Round 5
// baseline (113.307 us; speedup 1.0000x reference)
//
#include <hip/hip_runtime.h>

// SparseLookupTable via one-hot MFMA (data conventions HW-verified rounds 1-3):
//   out[b,o] = sum_k lut[inp[b,k], wgt[o,k]],  B=512, O=1024, K=128, LUT 256x256.
//   A_k[b, j] = lut[inp[b,k], j]   (f16 rows gathered from LDS, ds_read_b128)
//   B_k[j, o] = onehot(wgt[o,k])   (built in VALU registers)
// MFMA f32_16x16x32_f16, 8 K-steps of 32 cover the 256-wide one-hot dim.
//
// Round-5 = Round-4 resubmit (infra failure, kernel audited clean) with one
// hardening change: hipMemsetAsync -> zero_out kernel (graph-capture-safe).
//
// Round-4 design: A-read reuse 4 -> 8 (LDS-pipe was the bottleneck).
//   Tile 32(M) x 128(N), K-split 2: grid (8 otile, 16 btile, 2 ksp) = 256 blocks.
//   Wave = kg (16 waves x 4 kslices): each A b128 read feeds 8 MFMAs (8 nt),
//   each one-hot bb feeds 2 MFMAs (2 mt). A-reads/CU: 2048 -> 1024.
//   key2 select scheme: per nt state = (key2, lo, hi); key2 = 2*s* + wordpair.
//     bb = [tA?lo:0, tA?hi:0, tB?lo:0, tB?hi:0], tA=(key2==2s), tB=(key2==2s+1)
//     == the verified p[4]/sl scheme.
//   Indices packed: w u8x8 -> 1 ds_read_b64/kslice; i row-pair u16 -> 1 read.
//   K-split combine: zero_out + 2 deterministic (commutative) f32 atomicAdds/addr.

#define KDIM 128

typedef _Float16 f16x8 __attribute__((ext_vector_type(8)));
typedef float    f32x4 __attribute__((ext_vector_type(4)));

union F16Frag { uint4 u; f16x8 h; };

__global__ __launch_bounds__(256)
void zero_out(float* __restrict__ out) {
    ((float4*)out)[blockIdx.x * 256 + threadIdx.x] = float4{0.f, 0.f, 0.f, 0.f};
}

__global__ __launch_bounds__(1024, 4)
void slt_mfma(const int* __restrict__ inp, const int* __restrict__ wgt,
              const float* __restrict__ lut, float* __restrict__ out)
{
    // 131072 (LUT f16 swizzled) + 2048 (i_lds [64][16] u16 row-pairs)
    // + 8192 (w_lds [64][16][8] u8) = 141312 B
    __shared__ __attribute__((aligned(16))) unsigned char smem[141312];
    unsigned char*  lutB  = smem;
    unsigned short* i_lds = (unsigned short*)(smem + 131072);
    unsigned char*  w_lds = (unsigned char*)(smem + 133120);

    const int tid   = threadIdx.x;
    const int otile = blockIdx.x;   // 8 tiles of 128 outputs
    const int btile = blockIdx.y;   // 16 tiles of 32 batch rows
    const int ksp   = blockIdx.z;   // 2 K-splits of 64 kslices

    // ---- stage LUT fp32 -> fp16, chunk-XOR swizzled (verbatim round 3) ----
    // row r, logical byte lb (512/row), chunk = lb>>4 (16B units).
    // phys = r*512 + (((chunk&24) | ((chunk ^ (r&7)) & 7)) << 4) + (lb & 15)
    {
        const float4* lut4 = (const float4*)lut;
        #pragma unroll
        for (int it = 0; it < 16; ++it) {
            int idx = it * 1024 + tid;
            float4 v = lut4[idx];
            union { _Float16 h[4]; unsigned long long u; } pk;
            pk.h[0] = (_Float16)v.x; pk.h[1] = (_Float16)v.y;
            pk.h[2] = (_Float16)v.z; pk.h[3] = (_Float16)v.w;
            unsigned r  = (unsigned)idx >> 6;
            unsigned lb = ((unsigned)idx & 63u) << 3;
            unsigned ch = lb >> 4;
            unsigned sw = (ch & 24u) | ((ch ^ (r & 7u)) & 7u);
            unsigned off = (r << 9) + (sw << 4) + (lb & 15u);
            *(unsigned long long*)(lutB + off) = pk.u;
        }
    }

    // ---- stage i: [ks][colq] u16 = (row colq | row colq+16 << 8), local ks ----
    if (tid < 512) {
        int row = tid >> 4;            // 0..31
        int c4  = tid & 15;            // int4 group within this block's 64 k's
        int4 iv = *(const int4*)(inp + (size_t)(btile * 32 + row) * KDIM
                                     + ksp * 64 + c4 * 4);
        unsigned char* ib = (unsigned char*)i_lds;
        int sub = row >> 4, r15 = row & 15;
        int ks0 = c4 * 4;
        ib[(ks0+0)*32 + r15*2 + sub] = (unsigned char)(iv.x & 255);
        ib[(ks0+1)*32 + r15*2 + sub] = (unsigned char)(iv.y & 255);
        ib[(ks0+2)*32 + r15*2 + sub] = (unsigned char)(iv.z & 255);
        ib[(ks0+3)*32 + r15*2 + sub] = (unsigned char)(iv.w & 255);
    }

    // ---- stage w: w_lds[ks*128 + colq*8 + nt] = wgt[otile*128+nt*16+colq][k] ----
    {
        int o  = tid >> 3;             // 0..127 output within tile
        int kq = tid & 7;              // octet of local ks
        const int* wp = wgt + (size_t)(otile * 128 + o) * KDIM + ksp * 64 + kq * 8;
        int4 w0 = *(const int4*)wp;
        int4 w1 = *(const int4*)(wp + 4);
        unsigned char* wb = w_lds + (o & 15) * 8 + (o >> 4);
        int ksb = kq * 8;
        wb[(ksb+0)*128] = (unsigned char)(w0.x & 255);
        wb[(ksb+1)*128] = (unsigned char)(w0.y & 255);
        wb[(ksb+2)*128] = (unsigned char)(w0.z & 255);
        wb[(ksb+3)*128] = (unsigned char)(w0.w & 255);
        wb[(ksb+4)*128] = (unsigned char)(w1.x & 255);
        wb[(ksb+5)*128] = (unsigned char)(w1.y & 255);
        wb[(ksb+6)*128] = (unsigned char)(w1.z & 255);
        wb[(ksb+7)*128] = (unsigned char)(w1.w & 255);
    }
    __syncthreads();

    const int      lane = tid & 63;
    const int      wid  = tid >> 6;                 // 4 kslices: wid*4 .. wid*4+3
    const unsigned colq = (unsigned)(lane & 15);    // A row-lane / B col / D col
    const unsigned q    = (unsigned)((lane >> 4) & 3);

    f32x4 acc[2][8];
    #pragma unroll
    for (int a = 0; a < 2; ++a)
        #pragma unroll
        for (int n = 0; n < 8; ++n) { f32x4 z = {0.f,0.f,0.f,0.f}; acc[a][n] = z; }

    #pragma unroll 1
    for (int jj = 0; jj < 4; ++jj) {
        const int ks = wid * 4 + jj;            // local kslice 0..63

        // A rows for both 16-row M-tiles (packed pair read)
        unsigned ip = i_lds[ks * 16 + colq];
        unsigned r0 = ip & 255u, r1 = ip >> 8;
        unsigned L0 = q ^ (r0 & 7u), L1 = q ^ (r1 & 7u);
        const unsigned char* pA0  = lutB + ((r0 << 9) + (L0 << 4));
        const unsigned char* pA1  = lutB + ((r1 << 9) + (L1 << 4));
        const unsigned char* pA0o = pA0 + 64u - ((L0 & 4u) << 5);
        const unsigned char* pA1o = pA1 + 64u - ((L1 & 4u) << 5);

        // One-hot prep for 8 N-tiles from one b64 read
        unsigned long long wq =
            *(const unsigned long long*)(w_lds + ks * 128 + colq * 8);
        unsigned wlo = (unsigned)wq, whi = (unsigned)(wq >> 32);

        unsigned k2[8], lo[8], hi[8];
        #pragma unroll
        for (int nt = 0; nt < 8; ++nt) {
            unsigned wv = ((nt < 4 ? wlo : whi) >> ((nt & 3) * 8)) & 255u;
            // wv bits: [7:5]=s*, [4:3]=owning k-group, [2:0]=slot
            unsigned long long pk = 0x3C00ULL << ((wv & 3u) << 4);
            lo[nt] = (unsigned)pk; hi[nt] = (unsigned)(pk >> 32);
            unsigned key = ((wv >> 4) & 0x0Eu) | ((wv >> 2) & 1u); // 2*s* + wordpair
            k2[nt] = (((wv >> 3) & 3u) == q) ? key : 0xFFu;       // sentinel if not ours
        }

        // 8 MFMA K-steps; each bb feeds both M-tiles, each A-read feeds 8 nt
        #pragma unroll
        for (int s = 0; s < 8; ++s) {
            const unsigned disp = (unsigned)(s >> 1) * 128u;
            F16Frag a0, a1;
            a0.u = *(const uint4*)(((s & 1) ? pA0o : pA0) + disp);
            a1.u = *(const uint4*)(((s & 1) ? pA1o : pA1) + disp);
            #pragma unroll
            for (int nt = 0; nt < 8; ++nt) {
                F16Frag bb;
                bool tA = (k2[nt] == 2u * (unsigned)s);
                bool tB = (k2[nt] == 2u * (unsigned)s + 1u);
                bb.u.x = tA ? lo[nt] : 0u;
                bb.u.y = tA ? hi[nt] : 0u;
                bb.u.z = tB ? lo[nt] : 0u;
                bb.u.w = tB ? hi[nt] : 0u;
                acc[0][nt] = __builtin_amdgcn_mfma_f32_16x16x32_f16(a0.h, bb.h, acc[0][nt], 0, 0, 0);
                acc[1][nt] = __builtin_amdgcn_mfma_f32_16x16x32_f16(a1.h, bb.h, acc[1][nt], 0, 0, 0);
            }
        }
    }

    // ---- cross-wave K-reduction in dead LUT LDS (2 phases) + atomic combine ----
    __syncthreads();                      // all waves done reading lutB
    f32x4* red = (f32x4*)smem;            // 16 waves x 8 nt x 64 lanes = 128 KB
    #pragma unroll 1
    for (int mt = 0; mt < 2; ++mt) {
        #pragma unroll
        for (int nt = 0; nt < 8; ++nt)
            red[(wid * 8 + nt) * 64 + lane] = acc[mt][nt];
        __syncthreads();
        if (tid < 512) {
            const int nt = tid >> 6, ln = tid & 63;
            f32x4 s4 = {0.f, 0.f, 0.f, 0.f};
            #pragma unroll
            for (int w = 0; w < 16; ++w)
                s4 += red[(w * 8 + nt) * 64 + ln];
            // D layout: col = lane&15, row = (lane>>4)*4 + reg  (HW-verified)
            const int rrow = btile * 32 + mt * 16 + ((ln >> 4) & 3) * 4;
            const int ccol = otile * 128 + nt * 16 + (ln & 15);
            #pragma unroll
            for (int c = 0; c < 4; ++c)
                atomicAdd(&out[(size_t)(rrow + c) * 1024 + ccol], s4[c]);
        }
        __syncthreads();                  // protect red before next phase
    }
}

extern "C" void kernel_launch(void* const* d_in, const int* in_sizes, int n_in,
                              void* d_out, int out_size, void* d_ws, size_t ws_size,
                              hipStream_t stream) {
    const int*   inp = (const int*)d_in[0];    // (512, 32, 4) int32
    const int*   wgt = (const int*)d_in[1];    // (1024, 32, 4) int32
    const float* lut = (const float*)d_in[2];  // (256, 256) fp32
    float*       out = (float*)d_out;          // (512, 1024) fp32

    // zero output (graph-capture-safe), then accumulate both K-splits atomically
    zero_out<<<dim3(512), dim3(256), 0, stream>>>(out);
    dim3 grid(8, 16, 2);
    dim3 block(1024);
    slt_mfma<<<grid, block, 0, stream>>>(inp, wgt, lut, out);
}

// Round 6
// 112.496 us; speedup vs baseline: 1.0072x; 1.0072x over previous
//
#include <hip/hip_runtime.h>

// SparseLookupTable via one-hot MFMA (data conventions HW-verified rounds 1-5):
//   out[b,o] = sum_k lut[inp[b,k], wgt[o,k]],  B=512, O=1024, K=128, LUT 256x256.
//   A_k[b, j] = lut[inp[b,k], j]   (f16 rows gathered from LDS, ds_read_b128)
//   B_k[j, o] = onehot(wgt[o,k])   (built in VALU registers)
// MFMA f32_16x16x32_f16, 8 K-steps of 32 cover the 256-wide one-hot dim.
//
// Round-6: round-5 compute kept byte-identical; combine mechanism replaced.
//   Measured round-5: atomicAdd K-split combine = 165 MB HBM traffic (RMW at
//   memory side), dur 59us == HBM time. Now: each ksp block streams its partial
//   tile to d_ws (plain stores), tiny combine kernel adds the two partials.
//   Fallback to zero+atomic path if ws_size < 4 MB.

#define KDIM 128
#define OUT_FLOATS (512 * 1024)

typedef _Float16 f16x8 __attribute__((ext_vector_type(8)));
typedef float    f32x4 __attribute__((ext_vector_type(4)));

union F16Frag { uint4 u; f16x8 h; };

__global__ __launch_bounds__(256)
void zero_out(float* __restrict__ out) {
    ((float4*)out)[blockIdx.x * 256 + threadIdx.x] = float4{0.f, 0.f, 0.f, 0.f};
}

__global__ __launch_bounds__(256)
void combine2(float* __restrict__ out, const float* __restrict__ ws) {
    int i = blockIdx.x * 256 + threadIdx.x;
    float4 a = ((const float4*)ws)[i];
    float4 b = ((const float4*)(ws + OUT_FLOATS))[i];
    ((float4*)out)[i] = float4{a.x + b.x, a.y + b.y, a.z + b.z, a.w + b.w};
}

__global__ __launch_bounds__(1024, 4)
void slt_mfma(const int* __restrict__ inp, const int* __restrict__ wgt,
              const float* __restrict__ lut, float* __restrict__ dst,
              const int mode /* 1: dst=ws partials, 0: dst=out atomics */)
{
    // 131072 (LUT f16 swizzled) + 2048 (i_lds [64][16] u16 row-pairs)
    // + 8192 (w_lds [64][16][8] u8) = 141312 B
    __shared__ __attribute__((aligned(16))) unsigned char smem[141312];
    unsigned char*  lutB  = smem;
    unsigned short* i_lds = (unsigned short*)(smem + 131072);
    unsigned char*  w_lds = (unsigned char*)(smem + 133120);

    const int tid   = threadIdx.x;
    const int otile = blockIdx.x;   // 8 tiles of 128 outputs
    const int btile = blockIdx.y;   // 16 tiles of 32 batch rows
    const int ksp   = blockIdx.z;   // 2 K-splits of 64 kslices

    // ---- stage LUT fp32 -> fp16, chunk-XOR swizzled (verbatim round 3) ----
    // row r, logical byte lb (512/row), chunk = lb>>4 (16B units).
    // phys = r*512 + (((chunk&24) | ((chunk ^ (r&7)) & 7)) << 4) + (lb & 15)
    {
        const float4* lut4 = (const float4*)lut;
        #pragma unroll
        for (int it = 0; it < 16; ++it) {
            int idx = it * 1024 + tid;
            float4 v = lut4[idx];
            union { _Float16 h[4]; unsigned long long u; } pk;
            pk.h[0] = (_Float16)v.x; pk.h[1] = (_Float16)v.y;
            pk.h[2] = (_Float16)v.z; pk.h[3] = (_Float16)v.w;
            unsigned r  = (unsigned)idx >> 6;
            unsigned lb = ((unsigned)idx & 63u) << 3;
            unsigned ch = lb >> 4;
            unsigned sw = (ch & 24u) | ((ch ^ (r & 7u)) & 7u);
            unsigned off = (r << 9) + (sw << 4) + (lb & 15u);
            *(unsigned long long*)(lutB + off) = pk.u;
        }
    }

    // ---- stage i: [ks][colq] u16 = (row colq | row colq+16 << 8), local ks ----
    if (tid < 512) {
        int row = tid >> 4;            // 0..31
        int c4  = tid & 15;            // int4 group within this block's 64 k's
        int4 iv = *(const int4*)(inp + (size_t)(btile * 32 + row) * KDIM
                                     + ksp * 64 + c4 * 4);
        unsigned char* ib = (unsigned char*)i_lds;
        int sub = row >> 4, r15 = row & 15;
        int ks0 = c4 * 4;
        ib[(ks0+0)*32 + r15*2 + sub] = (unsigned char)(iv.x & 255);
        ib[(ks0+1)*32 + r15*2 + sub] = (unsigned char)(iv.y & 255);
        ib[(ks0+2)*32 + r15*2 + sub] = (unsigned char)(iv.z & 255);
        ib[(ks0+3)*32 + r15*2 + sub] = (unsigned char)(iv.w & 255);
    }

    // ---- stage w: w_lds[ks*128 + colq*8 + nt] = wgt[otile*128+nt*16+colq][k] ----
    {
        int o  = tid >> 3;             // 0..127 output within tile
        int kq = tid & 7;              // octet of local ks
        const int* wp = wgt + (size_t)(otile * 128 + o) * KDIM + ksp * 64 + kq * 8;
        int4 w0 = *(const int4*)wp;
        int4 w1 = *(const int4*)(wp + 4);
        unsigned char* wb = w_lds + (o & 15) * 8 + (o >> 4);
        int ksb = kq * 8;
        wb[(ksb+0)*128] = (unsigned char)(w0.x & 255);
        wb[(ksb+1)*128] = (unsigned char)(w0.y & 255);
        wb[(ksb+2)*128] = (unsigned char)(w0.z & 255);
        wb[(ksb+3)*128] = (unsigned char)(w0.w & 255);
        wb[(ksb+4)*128] = (unsigned char)(w1.x & 255);
        wb[(ksb+5)*128] = (unsigned char)(w1.y & 255);
        wb[(ksb+6)*128] = (unsigned char)(w1.z & 255);
        wb[(ksb+7)*128] = (unsigned char)(w1.w & 255);
    }
    __syncthreads();

    const int      lane = tid & 63;
    const int      wid  = tid >> 6;                 // 4 kslices: wid*4 .. wid*4+3
    const unsigned colq = (unsigned)(lane & 15);    // A row-lane / B col / D col
    const unsigned q    = (unsigned)((lane >> 4) & 3);

    f32x4 acc[2][8];
    #pragma unroll
    for (int a = 0; a < 2; ++a)
        #pragma unroll
        for (int n = 0; n < 8; ++n) { f32x4 z = {0.f,0.f,0.f,0.f}; acc[a][n] = z; }

    #pragma unroll 1
    for (int jj = 0; jj < 4; ++jj) {
        const int ks = wid * 4 + jj;            // local kslice 0..63

        // A rows for both 16-row M-tiles (packed pair read)
        unsigned ip = i_lds[ks * 16 + colq];
        unsigned r0 = ip & 255u, r1 = ip >> 8;
        unsigned L0 = q ^ (r0 & 7u), L1 = q ^ (r1 & 7u);
        const unsigned char* pA0  = lutB + ((r0 << 9) + (L0 << 4));
        const unsigned char* pA1  = lutB + ((r1 << 9) + (L1 << 4));
        const unsigned char* pA0o = pA0 + 64u - ((L0 & 4u) << 5);
        const unsigned char* pA1o = pA1 + 64u - ((L1 & 4u) << 5);

        // One-hot prep for 8 N-tiles from one b64 read
        unsigned long long wq =
            *(const unsigned long long*)(w_lds + ks * 128 + colq * 8);
        unsigned wlo = (unsigned)wq, whi = (unsigned)(wq >> 32);

        unsigned k2[8], lo[8], hi[8];
        #pragma unroll
        for (int nt = 0; nt < 8; ++nt) {
            unsigned wv = ((nt < 4 ? wlo : whi) >> ((nt & 3) * 8)) & 255u;
            // wv bits: [7:5]=s*, [4:3]=owning k-group, [2:0]=slot
            unsigned long long pk = 0x3C00ULL << ((wv & 3u) << 4);
            lo[nt] = (unsigned)pk; hi[nt] = (unsigned)(pk >> 32);
            unsigned key = ((wv >> 4) & 0x0Eu) | ((wv >> 2) & 1u); // 2*s* + wordpair
            k2[nt] = (((wv >> 3) & 3u) == q) ? key : 0xFFu;       // sentinel if not ours
        }

        // 8 MFMA K-steps; each bb feeds both M-tiles, each A-read feeds 8 nt
        #pragma unroll
        for (int s = 0; s < 8; ++s) {
            const unsigned disp = (unsigned)(s >> 1) * 128u;
            F16Frag a0, a1;
            a0.u = *(const uint4*)(((s & 1) ? pA0o : pA0) + disp);
            a1.u = *(const uint4*)(((s & 1) ? pA1o : pA1) + disp);
            #pragma unroll
            for (int nt = 0; nt < 8; ++nt) {
                F16Frag bb;
                bool tA = (k2[nt] == 2u * (unsigned)s);
                bool tB = (k2[nt] == 2u * (unsigned)s + 1u);
                bb.u.x = tA ? lo[nt] : 0u;
                bb.u.y = tA ? hi[nt] : 0u;
                bb.u.z = tB ? lo[nt] : 0u;
                bb.u.w = tB ? hi[nt] : 0u;
                acc[0][nt] = __builtin_amdgcn_mfma_f32_16x16x32_f16(a0.h, bb.h, acc[0][nt], 0, 0, 0);
                acc[1][nt] = __builtin_amdgcn_mfma_f32_16x16x32_f16(a1.h, bb.h, acc[1][nt], 0, 0, 0);
            }
        }
    }

    // ---- cross-wave K-reduction in dead LUT LDS (2 phases), then combine ----
    __syncthreads();                      // all waves done reading lutB
    float* outp = mode ? (dst + (size_t)ksp * OUT_FLOATS) : dst;
    f32x4* red = (f32x4*)smem;            // 16 waves x 8 nt x 64 lanes = 128 KB
    #pragma unroll 1
    for (int mt = 0; mt < 2; ++mt) {
        #pragma unroll
        for (int nt = 0; nt < 8; ++nt)
            red[(wid * 8 + nt) * 64 + lane] = acc[mt][nt];
        __syncthreads();
        if (tid < 512) {
            const int nt = tid >> 6, ln = tid & 63;
            f32x4 s4 = {0.f, 0.f, 0.f, 0.f};
            #pragma unroll
            for (int w = 0; w < 16; ++w)
                s4 += red[(w * 8 + nt) * 64 + ln];
            // D layout: col = lane&15, row = (lane>>4)*4 + reg  (HW-verified)
            const int rrow = btile * 32 + mt * 16 + ((ln >> 4) & 3) * 4;
            const int ccol = otile * 128 + nt * 16 + (ln & 15);
            #pragma unroll
            for (int c = 0; c < 4; ++c) {
                size_t addr = (size_t)(rrow + c) * 1024 + ccol;
                if (mode) outp[addr] = s4[c];
                else      atomicAdd(&outp[addr], s4[c]);
            }
        }
        __syncthreads();                  // protect red before next phase
    }
}

extern "C" void kernel_launch(void* const* d_in, const int* in_sizes, int n_in,
                              void* d_out, int out_size, void* d_ws, size_t ws_size,
                              hipStream_t stream) {
    const int*   inp = (const int*)d_in[0];    // (512, 32, 4) int32
    const int*   wgt = (const int*)d_in[1];    // (1024, 32, 4) int32
    const float* lut = (const float*)d_in[2];  // (256, 256) fp32
    float*       out = (float*)d_out;          // (512, 1024) fp32

    dim3 grid(8, 16, 2);
    dim3 block(1024);

    if (ws_size >= (size_t)2 * OUT_FLOATS * sizeof(float)) {
        // partials into workspace (plain streaming stores), then tiny combine
        float* ws = (float*)d_ws;
        slt_mfma<<<grid, block, 0, stream>>>(inp, wgt, lut, ws, 1);
        combine2<<<dim3(512), dim3(256), 0, stream>>>(out, ws);
    } else {
        // fallback: zero + deterministic commutative atomics (round-5 verified)
        zero_out<<<dim3(512), dim3(256), 0, stream>>>(out);
        slt_mfma<<<grid, block, 0, stream>>>(inp, wgt, lut, out, 0);
    }
}